// Round 15
// baseline (598.211 us; speedup 1.0000x reference)
//
#include <hip/hip_runtime.h>
#include <stdint.h>

#define NN 50000
#define RR 64
#define EE 20000
#define NB 16            // bases
#define IND 256
#define OUTD 256
#define KK 4352          // 16*256 (V) + 256 (x for root)
#define NE (RR * EE)     // 1,280,000 edges
#define GITER 68         // KK / 64
#define SCANB 49         // ceil(NN/1024)

typedef __attribute__((ext_vector_type(8))) short bf16x8;
typedef __attribute__((ext_vector_type(4))) float f32x4;
typedef __attribute__((ext_vector_type(2))) float f32x2;
typedef __attribute__((ext_vector_type(2))) unsigned int u32x2;

__device__ __forceinline__ unsigned short f2bf(float f) {
  union { float f; unsigned u; } v; v.f = f;
  unsigned r = v.u + 0x7FFFu + ((v.u >> 16) & 1u);   // RNE
  return (unsigned short)(r >> 16);
}
__device__ __forceinline__ float asf(unsigned u) {
  union { unsigned u; float f; } v; v.u = u; return v.f;
}

// ---------- x -> bf16, chunk-swizzled: chunk ch of row r stored at ch^(r&7) ----------
__global__ __launch_bounds__(256) void k_xbf(const float* __restrict__ x,
                                             unsigned short* __restrict__ xsw) {
  const int gt = blockIdx.x * 256 + threadIdx.x;     // one 8-elem chunk per thread
  const size_t g = (size_t)gt * 8;
  const int row = gt >> 5;                           // g / 256
  const int k = (gt & 31) * 8;                       // g % 256
  float4 v0 = *reinterpret_cast<const float4*>(x + g);
  float4 v1 = *reinterpret_cast<const float4*>(x + g + 4);
  union { bf16x8 v; unsigned short u[8]; } pk;
  pk.u[0]=f2bf(v0.x); pk.u[1]=f2bf(v0.y); pk.u[2]=f2bf(v0.z); pk.u[3]=f2bf(v0.w);
  pk.u[4]=f2bf(v1.x); pk.u[5]=f2bf(v1.y); pk.u[6]=f2bf(v1.z); pk.u[7]=f2bf(v1.w);
  const int tile = k >> 6, ch = (k >> 3) & 7;
  *reinterpret_cast<bf16x8*>(
      xsw + (size_t)row * 256 + tile * 64 + ((ch ^ (row & 7)) << 3)) = pk.v;
}

// ---------- counting sort of edges by dst ----------
__global__ __launch_bounds__(256) void k_hist(const int* __restrict__ edst,
                                              int* __restrict__ cnt) {
  const int g = blockIdx.x * 256 + threadIdx.x;
  atomicAdd(&cnt[edst[g]], 1);
}

__global__ __launch_bounds__(256) void k_scan_a(const int* __restrict__ cnt,
                                                int* __restrict__ rowptr,
                                                int* __restrict__ bsum) {
  __shared__ int ps[256];
  const int t = threadIdx.x, blk = blockIdx.x;
  const int base = blk * 1024 + t * 4;
  int v[4];
#pragma unroll
  for (int q = 0; q < 4; ++q) {
    const int idx = base + q;
    v[q] = (idx < NN) ? cnt[idx] : 0;
  }
  const int s = v[0] + v[1] + v[2] + v[3];
  ps[t] = s;
  __syncthreads();
  for (int off = 1; off < 256; off <<= 1) {
    const int u = (t >= off) ? ps[t - off] : 0;
    __syncthreads();
    ps[t] += u;
    __syncthreads();
  }
  int run = ps[t] - s;
#pragma unroll
  for (int q = 0; q < 4; ++q) {
    const int idx = base + q;
    if (idx < NN) rowptr[idx] = run;
    run += v[q];
  }
  if (t == 255) bsum[blk] = ps[255];
}

__global__ __launch_bounds__(64) void k_scan_b(const int* __restrict__ bsum,
                                               int* __restrict__ boff,
                                               int* __restrict__ rowptr) {
  const int t = threadIdx.x;
  const int own = (t < SCANB) ? bsum[t] : 0;
  int v = own;
  for (int off = 1; off < 64; off <<= 1) {
    const int u = __shfl_up(v, off);
    if (t >= off) v += u;
  }
  if (t < SCANB) boff[t] = v - own;
  if (t == SCANB - 1) rowptr[NN] = v;
}

__global__ __launch_bounds__(256) void k_scan_c(const int* __restrict__ boff,
                                                int* __restrict__ rowptr,
                                                int* __restrict__ wof) {
  const int t = threadIdx.x, blk = blockIdx.x;
  const int base = blk * 1024 + t * 4;
  const int bo = boff[blk];
#pragma unroll
  for (int q = 0; q < 4; ++q) {
    const int idx = base + q;
    if (idx < NN) {
      const int val = rowptr[idx] + bo;
      rowptr[idx] = val;
      wof[idx] = val;
    }
  }
}

__global__ __launch_bounds__(256) void k_scatter(const int* __restrict__ esrc,
                                                 const int* __restrict__ edst,
                                                 int* __restrict__ wof,
                                                 unsigned* __restrict__ payload) {
  const int g = blockIdx.x * 256 + threadIdx.x;
  const int d = edst[g];
  const int src = esrc[g];
  const int r = g / EE;
  const int pos = atomicAdd(&wof[d], 1);
  payload[pos] = ((unsigned)r << 18) | (unsigned)src;
}

// ---------- bt[o][k] bf16, chunk-swizzled by (o&7) ----------
__global__ __launch_bounds__(256) void k_bt(const float* __restrict__ basis,
                                            const float* __restrict__ root,
                                            unsigned short* __restrict__ bt) {
  const int o = blockIdx.x;
  for (int k = threadIdx.x; k < KK; k += 256) {
    float v;
    if (k < 4096) v = basis[(size_t)k * 256 + o];
    else          v = root[(size_t)(k - 4096) * 256 + o];
    const int tile = k >> 6, ch = (k >> 3) & 7;
    bt[(size_t)o * KK + tile * 64 + ((ch ^ (o & 7)) << 3) + (k & 7)] = f2bf(v);
  }
}

// ---------- V-build: one wave per dst; 4-deep pipelined gather; nt swizzle-baked V store ----------
__global__ __launch_bounds__(128) void k_vbuild(
    const unsigned short* __restrict__ xsw, const float* __restrict__ att,
    const float* __restrict__ deg, const int* __restrict__ rowptr,
    const unsigned* __restrict__ payload, unsigned short* __restrict__ Vb,
    const int c0) {
  __shared__ float attl[RR * NB];                    // 4 KB
  const int t = threadIdx.x;
  *reinterpret_cast<float4*>(&attl[t * 8]) =
      *reinterpret_cast<const float4*>(&att[t * 8]);
  *reinterpret_cast<float4*>(&attl[t * 8 + 4]) =
      *reinterpret_cast<const float4*>(&att[t * 8 + 4]);
  __syncthreads();
  const int lane = t & 63;
  const int n = c0 + blockIdx.x * 2 + (t >> 6);      // 2 waves/block: less imbalance
  if (n >= NN) return;
  const int k0 = rowptr[n], k1 = rowptr[n + 1];

  const int laneBase = (lane >> 4) * 64 + (lane & 1) * 4;
  const unsigned laneCh = (unsigned)((lane >> 1) & 7);

  f32x2 acc2[NB][2];
#pragma unroll
  for (int b = 0; b < NB; ++b) {
    acc2[b][0] = (f32x2){0.f, 0.f};
    acc2[b][1] = (f32x2){0.f, 0.f};
  }

#define XLOAD(PK)                                                            \
  (*reinterpret_cast<const uint2*>(                                          \
      xsw + (size_t)((PK) & 0x3FFFFu) * 256 + laneBase +                     \
      ((laneCh ^ ((PK) & 7u)) << 3)))

#define PROC(J, PK, XV)                                                      \
  {                                                                          \
    const bool ok_ = (k + (J)) < k1;                                         \
    const unsigned mx_ = ok_ ? (XV).x : 0u;                                  \
    const unsigned my_ = ok_ ? (XV).y : 0u;                                  \
    const int r_ = (int)((PK) >> 18);                                        \
    const f32x2 x01_ = {asf(mx_ << 16), asf(mx_ & 0xFFFF0000u)};             \
    const f32x2 x23_ = {asf(my_ << 16), asf(my_ & 0xFFFF0000u)};             \
    _Pragma("unroll")                                                        \
    for (int b4 = 0; b4 < 4; ++b4) {                                         \
      const float4 a4 = *reinterpret_cast<const float4*>(&attl[r_ * NB + b4 * 4]); \
      const float aa[4] = {a4.x, a4.y, a4.z, a4.w};                          \
      _Pragma("unroll")                                                      \
      for (int q = 0; q < 4; ++q) {                                          \
        const int b = b4 * 4 + q;                                            \
        acc2[b][0] += aa[q] * x01_;                                          \
        acc2[b][1] += aa[q] * x23_;                                          \
      }                                                                      \
    }                                                                        \
  }

  // 4-deep, two-level pipeline (payload 16-entry zero pad makes over-reads safe)
  unsigned p0 = payload[k0],     p1 = payload[k0 + 1];
  unsigned p2 = payload[k0 + 2], p3 = payload[k0 + 3];
  uint2 x0 = XLOAD(p0), x1 = XLOAD(p1), x2 = XLOAD(p2), x3 = XLOAD(p3);
  unsigned q0 = payload[k0 + 4], q1 = payload[k0 + 5];
  unsigned q2 = payload[k0 + 6], q3 = payload[k0 + 7];

  for (int k = k0; k < k1; k += 4) {
    const uint2 nx0 = XLOAD(q0), nx1 = XLOAD(q1);    // x for group g+1 (q* arrived)
    const uint2 nx2 = XLOAD(q2), nx3 = XLOAD(q3);
    const unsigned r0 = payload[k + 8],  r1 = payload[k + 9];   // payload for g+2
    const unsigned r2 = payload[k + 10], r3 = payload[k + 11];
    PROC(0, p0, x0) PROC(1, p1, x1) PROC(2, p2, x2) PROC(3, p3, x3)
    p0 = q0; p1 = q1; p2 = q2; p3 = q3;
    q0 = r0; q1 = r1; q2 = r2; q3 = r3;
    x0 = nx0; x1 = nx1; x2 = nx2; x3 = nx3;
  }

  const float iv = 1.0f / deg[n];
  const int nl = n - c0;
  unsigned short* vr = Vb + (size_t)nl * 4096 + (lane >> 4) * 64 +
                       ((((unsigned)(lane >> 1) & 7u) ^ (unsigned)(nl & 7)) << 3) +
                       (lane & 1) * 4;
#pragma unroll
  for (int b = 0; b < NB; ++b) {
    const unsigned short s0 = f2bf(acc2[b][0].x * iv);
    const unsigned short s1 = f2bf(acc2[b][0].y * iv);
    const unsigned short s2 = f2bf(acc2[b][1].x * iv);
    const unsigned short s3 = f2bf(acc2[b][1].y * iv);
    u32x2 pk;
    pk.x = (unsigned)s0 | ((unsigned)s1 << 16);
    pk.y = (unsigned)s2 | ((unsigned)s3 << 16);
    __builtin_nontemporal_store(pk, reinterpret_cast<u32x2*>(vr + (size_t)b * 256));
  }
}

// ---------- GEMM: out = [V/deg | x] @ bt^T, 64x128 tile, 2 waves, single-buf 24KB ----------
__global__ __launch_bounds__(128) void k_gemm6(
    const unsigned short* __restrict__ Vb, const unsigned short* __restrict__ xsw,
    const unsigned short* __restrict__ bt, float* __restrict__ out, const int c0) {
  __shared__ unsigned short As[64 * 64];             // 8 KB
  __shared__ unsigned short Bs[128 * 64];            // 16 KB
  const int t = threadIdx.x;
  const int rb = blockIdx.x, cb = blockIdx.y;
  const int lane = t & 63, w = t >> 6;               // 2 waves: cols w*64..+64
  const int lc = lane & 15, lg = lane >> 4;

  // staging roles: round covers 16 rows(A)/cols(B); row = r*16 + (t>>3), pos = t&7
  const int srow = t >> 3;                           // 0..15
  const int spos = t & 7;                            // chunk position (pre-swizzled src)
  const unsigned short* va[4];
  const unsigned short* xa[4];
  const unsigned short* bb[8];
#pragma unroll
  for (int a = 0; a < 4; ++a) {
    const int rl = a * 16 + srow;                    // 0..63 local row
    va[a] = Vb  + (size_t)(rb * 64 + rl) * 4096 + spos * 8;
    xa[a] = xsw + (size_t)(c0 + rb * 64 + rl) * 256 + spos * 8;
  }
#pragma unroll
  for (int b = 0; b < 8; ++b) {
    const int cl = b * 16 + srow;                    // 0..127 local col
    bb[b] = bt + (size_t)(cb * 128 + cl) * KK + spos * 8;
  }

#define GL(G, L) __builtin_amdgcn_global_load_lds(                            \
    (const __attribute__((address_space(1))) unsigned int*)(G),               \
    (__attribute__((address_space(3))) unsigned int*)(L), 16, 0, 0)

#define STAGE6(IT)                                                            \
  {                                                                           \
    const int it_ = (IT);                                                     \
    if (it_ < 64) {                                                           \
      _Pragma("unroll")                                                       \
      for (int a = 0; a < 4; ++a)                                             \
        GL(va[a] + it_ * 64, As + a * 1024 + (w << 9));                       \
    } else {                                                                  \
      _Pragma("unroll")                                                       \
      for (int a = 0; a < 4; ++a)                                             \
        GL(xa[a] + (it_ - 64) * 64, As + a * 1024 + (w << 9));                \
    }                                                                         \
    _Pragma("unroll")                                                         \
    for (int b = 0; b < 8; ++b)                                               \
      GL(bb[b] + it_ * 64, Bs + b * 1024 + (w << 9));                         \
  }

  f32x4 acc[4][4];
  const f32x4 zf = {0.f, 0.f, 0.f, 0.f};
#pragma unroll
  for (int m = 0; m < 4; ++m)
#pragma unroll
    for (int n = 0; n < 4; ++n) acc[m][n] = zf;

  for (int it = 0; it < GITER; ++it) {
    __syncthreads();                                 // previous iter's LDS reads done
    STAGE6(it);
    asm volatile("s_waitcnt vmcnt(0)" ::: "memory");
    __syncthreads();                                 // staged tile visible
#pragma unroll
    for (int kk = 0; kk < 2; ++kk) {
      bf16x8 af[4], bfm[4];
      const int ch = kk * 4 + lg;
#pragma unroll
      for (int m = 0; m < 4; ++m) {
        const int r2 = m * 16 + lc;                  // A rows 0..63
        af[m] = *reinterpret_cast<const bf16x8*>(&As[r2 * 64 + ((ch ^ (r2 & 7)) << 3)]);
      }
#pragma unroll
      for (int n = 0; n < 4; ++n) {
        const int c2 = w * 64 + n * 16 + lc;         // B cols per wave
        bfm[n] = *reinterpret_cast<const bf16x8*>(&Bs[c2 * 64 + ((ch ^ (c2 & 7)) << 3)]);
      }
#pragma unroll
      for (int m = 0; m < 4; ++m)
#pragma unroll
        for (int n = 0; n < 4; ++n)
          acc[m][n] = __builtin_amdgcn_mfma_f32_16x16x32_bf16(af[m], bfm[n], acc[m][n], 0, 0, 0);
    }
  }
#pragma unroll
  for (int m = 0; m < 4; ++m) {
#pragma unroll
    for (int j = 0; j < 4; ++j) {
      const int n = c0 + rb * 64 + m * 16 + lg * 4 + j;
      if (n < NN) {
        float* orow = out + (size_t)n * OUTD + cb * 128 + w * 64 + lc;
        __builtin_nontemporal_store(acc[m][0][j], orow + 0);
        __builtin_nontemporal_store(acc[m][1][j], orow + 16);
        __builtin_nontemporal_store(acc[m][2][j], orow + 32);
        __builtin_nontemporal_store(acc[m][3][j], orow + 48);
      }
    }
  }
}

extern "C" void kernel_launch(void* const* d_in, const int* in_sizes, int n_in,
                              void* d_out, int out_size, void* d_ws, size_t ws_size,
                              hipStream_t stream) {
  (void)in_sizes; (void)n_in; (void)out_size;
  const float* x     = (const float*)d_in[0];
  const float* att   = (const float*)d_in[1];
  const float* basis = (const float*)d_in[2];
  const float* root  = (const float*)d_in[3];
  const float* deg   = (const float*)d_in[4];
  const int*   esrc  = (const int*)d_in[5];
  const int*   edst  = (const int*)d_in[6];
  float* out = (float*)d_out;

  char* p = (char*)d_ws;
  unsigned short* xsw  = (unsigned short*)p; p += (size_t)NN * IND * 2;     // 25.6 MB
  unsigned short* bt   = (unsigned short*)p; p += (size_t)OUTD * KK * 2;    // 2.2 MB
  unsigned* payload    = (unsigned*)p;       p += (size_t)(NE + 16) * 4;    // 5.1 MB (+pad)
  int* rowptr          = (int*)p;            p += (size_t)(NN + 1) * 4;
  int* wof             = (int*)p;            p += (size_t)NN * 4;
  int* cnt             = (int*)p;            p += (size_t)NN * 4;
  int* bsum            = (int*)p;            p += 64 * 4;
  int* boff            = (int*)p;            p += 64 * 4;
  uintptr_t up = ((uintptr_t)p + 255) & ~(uintptr_t)255;
  unsigned short* Vb  = (unsigned short*)up;
  const size_t used = (size_t)((char*)Vb - (char*)d_ws);
  const size_t avail = ws_size - used;

  int chunk;
  if      (avail >= (size_t)(NN + 128) * 4096 * 2) chunk = NN;     // 410.7 MB: single pass
  else if (avail >= (size_t)25600 * 4096 * 2)      chunk = 25600;  // 209.7 MB
  else                                             chunk = 12800;

  hipMemsetAsync(cnt, 0, (size_t)NN * 4, stream);
  hipMemsetAsync(payload + NE, 0, 64, stream);       // zero the prefetch pad
  hipLaunchKernelGGL(k_xbf,     dim3(NN * IND / 2048), dim3(256),  0, stream, x, xsw);
  hipLaunchKernelGGL(k_hist,    dim3(NE / 256),        dim3(256),  0, stream, edst, cnt);
  hipLaunchKernelGGL(k_scan_a,  dim3(SCANB),           dim3(256),  0, stream, cnt, rowptr, bsum);
  hipLaunchKernelGGL(k_scan_b,  dim3(1),               dim3(64),   0, stream, bsum, boff, rowptr);
  hipLaunchKernelGGL(k_scan_c,  dim3(SCANB),           dim3(256),  0, stream, boff, rowptr, wof);
  hipLaunchKernelGGL(k_scatter, dim3(NE / 256),        dim3(256),  0, stream, esrc, edst, wof, payload);
  hipLaunchKernelGGL(k_bt,      dim3(OUTD),            dim3(256),  0, stream, basis, root, bt);

  for (int c0 = 0; c0 < NN; c0 += chunk) {
    const int rows = (NN - c0 < chunk) ? (NN - c0) : chunk;
    hipLaunchKernelGGL(k_vbuild, dim3((rows + 1) / 2), dim3(128), 0, stream,
                       xsw, att, deg, rowptr, payload, Vb, c0);
    hipLaunchKernelGGL(k_gemm6, dim3((rows + 63) / 64, 2), dim3(128), 0, stream,
                       Vb, xsw, bt, out, c0);
  }
}

// Round 16
// 595.882 us; speedup vs baseline: 1.0039x; 1.0039x over previous
//
#include <hip/hip_runtime.h>
#include <stdint.h>

#define NN 50000
#define RR 64
#define EE 20000
#define NB 16            // bases
#define IND 256
#define OUTD 256
#define KK 4352          // 16*256 (V) + 256 (x for root)
#define NE (RR * EE)     // 1,280,000 edges
#define GITER 68         // KK / 64
#define SCANB 49         // ceil(NN/1024)

typedef __attribute__((ext_vector_type(8))) short bf16x8;
typedef __attribute__((ext_vector_type(4))) float f32x4;
typedef __attribute__((ext_vector_type(2))) float f32x2;
typedef __attribute__((ext_vector_type(2))) unsigned int u32x2;

__device__ __forceinline__ unsigned short f2bf(float f) {
  union { float f; unsigned u; } v; v.f = f;
  unsigned r = v.u + 0x7FFFu + ((v.u >> 16) & 1u);   // RNE
  return (unsigned short)(r >> 16);
}
__device__ __forceinline__ float asf(unsigned u) {
  union { unsigned u; float f; } v; v.u = u; return v.f;
}

// ---------- x -> bf16, chunk-swizzled: chunk ch of row r stored at ch^(r&7) ----------
__global__ __launch_bounds__(256) void k_xbf(const float* __restrict__ x,
                                             unsigned short* __restrict__ xsw) {
  const int gt = blockIdx.x * 256 + threadIdx.x;     // one 8-elem chunk per thread
  const size_t g = (size_t)gt * 8;
  const int row = gt >> 5;                           // g / 256
  const int k = (gt & 31) * 8;                       // g % 256
  float4 v0 = *reinterpret_cast<const float4*>(x + g);
  float4 v1 = *reinterpret_cast<const float4*>(x + g + 4);
  union { bf16x8 v; unsigned short u[8]; } pk;
  pk.u[0]=f2bf(v0.x); pk.u[1]=f2bf(v0.y); pk.u[2]=f2bf(v0.z); pk.u[3]=f2bf(v0.w);
  pk.u[4]=f2bf(v1.x); pk.u[5]=f2bf(v1.y); pk.u[6]=f2bf(v1.z); pk.u[7]=f2bf(v1.w);
  const int tile = k >> 6, ch = (k >> 3) & 7;
  *reinterpret_cast<bf16x8*>(
      xsw + (size_t)row * 256 + tile * 64 + ((ch ^ (row & 7)) << 3)) = pk.v;
}

// ---------- counting sort of edges by dst ----------
__global__ __launch_bounds__(256) void k_hist(const int* __restrict__ edst,
                                              int* __restrict__ cnt) {
  const int g = blockIdx.x * 256 + threadIdx.x;
  atomicAdd(&cnt[edst[g]], 1);
}

__global__ __launch_bounds__(256) void k_scan_a(const int* __restrict__ cnt,
                                                int* __restrict__ rowptr,
                                                int* __restrict__ bsum) {
  __shared__ int ps[256];
  const int t = threadIdx.x, blk = blockIdx.x;
  const int base = blk * 1024 + t * 4;
  int v[4];
#pragma unroll
  for (int q = 0; q < 4; ++q) {
    const int idx = base + q;
    v[q] = (idx < NN) ? cnt[idx] : 0;
  }
  const int s = v[0] + v[1] + v[2] + v[3];
  ps[t] = s;
  __syncthreads();
  for (int off = 1; off < 256; off <<= 1) {
    const int u = (t >= off) ? ps[t - off] : 0;
    __syncthreads();
    ps[t] += u;
    __syncthreads();
  }
  int run = ps[t] - s;
#pragma unroll
  for (int q = 0; q < 4; ++q) {
    const int idx = base + q;
    if (idx < NN) rowptr[idx] = run;
    run += v[q];
  }
  if (t == 255) bsum[blk] = ps[255];
}

__global__ __launch_bounds__(64) void k_scan_b(const int* __restrict__ bsum,
                                               int* __restrict__ boff,
                                               int* __restrict__ rowptr) {
  const int t = threadIdx.x;
  const int own = (t < SCANB) ? bsum[t] : 0;
  int v = own;
  for (int off = 1; off < 64; off <<= 1) {
    const int u = __shfl_up(v, off);
    if (t >= off) v += u;
  }
  if (t < SCANB) boff[t] = v - own;
  if (t == SCANB - 1) rowptr[NN] = v;
}

__global__ __launch_bounds__(256) void k_scan_c(const int* __restrict__ boff,
                                                int* __restrict__ rowptr,
                                                int* __restrict__ wof) {
  const int t = threadIdx.x, blk = blockIdx.x;
  const int base = blk * 1024 + t * 4;
  const int bo = boff[blk];
#pragma unroll
  for (int q = 0; q < 4; ++q) {
    const int idx = base + q;
    if (idx < NN) {
      const int val = rowptr[idx] + bo;
      rowptr[idx] = val;
      wof[idx] = val;
    }
  }
}

__global__ __launch_bounds__(256) void k_scatter(const int* __restrict__ esrc,
                                                 const int* __restrict__ edst,
                                                 int* __restrict__ wof,
                                                 unsigned* __restrict__ payload) {
  const int g = blockIdx.x * 256 + threadIdx.x;
  const int d = edst[g];
  const int src = esrc[g];
  const int r = g / EE;
  const int pos = atomicAdd(&wof[d], 1);
  payload[pos] = ((unsigned)r << 18) | (unsigned)src;
}

// ---------- bt[o][k] bf16, chunk-swizzled by (o&7) ----------
__global__ __launch_bounds__(256) void k_bt(const float* __restrict__ basis,
                                            const float* __restrict__ root,
                                            unsigned short* __restrict__ bt) {
  const int o = blockIdx.x;
  for (int k = threadIdx.x; k < KK; k += 256) {
    float v;
    if (k < 4096) v = basis[(size_t)k * 256 + o];
    else          v = root[(size_t)(k - 4096) * 256 + o];
    const int tile = k >> 6, ch = (k >> 3) & 7;
    bt[(size_t)o * KK + tile * 64 + ((ch ^ (o & 7)) << 3) + (k & 7)] = f2bf(v);
  }
}

// ---------- V-build: one wave per dst; 4-deep pipelined gather; nt swizzle-baked V store ----------
__global__ __launch_bounds__(128) void k_vbuild(
    const unsigned short* __restrict__ xsw, const float* __restrict__ att,
    const float* __restrict__ deg, const int* __restrict__ rowptr,
    const unsigned* __restrict__ payload, unsigned short* __restrict__ Vb,
    const int c0) {
  __shared__ float attl[RR * NB];                    // 4 KB
  const int t = threadIdx.x;
  *reinterpret_cast<float4*>(&attl[t * 8]) =
      *reinterpret_cast<const float4*>(&att[t * 8]);
  *reinterpret_cast<float4*>(&attl[t * 8 + 4]) =
      *reinterpret_cast<const float4*>(&att[t * 8 + 4]);
  __syncthreads();
  const int lane = t & 63;
  const int n = c0 + blockIdx.x * 2 + (t >> 6);      // 2 waves/block: less imbalance
  if (n >= NN) return;
  const int k0 = rowptr[n], k1 = rowptr[n + 1];

  const int laneBase = (lane >> 4) * 64 + (lane & 1) * 4;
  const unsigned laneCh = (unsigned)((lane >> 1) & 7);

  f32x2 acc2[NB][2];
#pragma unroll
  for (int b = 0; b < NB; ++b) {
    acc2[b][0] = (f32x2){0.f, 0.f};
    acc2[b][1] = (f32x2){0.f, 0.f};
  }

#define XLOAD(PK)                                                            \
  (*reinterpret_cast<const uint2*>(                                          \
      xsw + (size_t)((PK) & 0x3FFFFu) * 256 + laneBase +                     \
      ((laneCh ^ ((PK) & 7u)) << 3)))

#define PROC(J, PK, XV)                                                      \
  {                                                                          \
    const bool ok_ = (k + (J)) < k1;                                         \
    const unsigned mx_ = ok_ ? (XV).x : 0u;                                  \
    const unsigned my_ = ok_ ? (XV).y : 0u;                                  \
    const int r_ = (int)((PK) >> 18);                                        \
    const f32x2 x01_ = {asf(mx_ << 16), asf(mx_ & 0xFFFF0000u)};             \
    const f32x2 x23_ = {asf(my_ << 16), asf(my_ & 0xFFFF0000u)};             \
    _Pragma("unroll")                                                        \
    for (int b4 = 0; b4 < 4; ++b4) {                                         \
      const float4 a4 = *reinterpret_cast<const float4*>(&attl[r_ * NB + b4 * 4]); \
      const float aa[4] = {a4.x, a4.y, a4.z, a4.w};                          \
      _Pragma("unroll")                                                      \
      for (int q = 0; q < 4; ++q) {                                          \
        const int b = b4 * 4 + q;                                            \
        acc2[b][0] += aa[q] * x01_;                                          \
        acc2[b][1] += aa[q] * x23_;                                          \
      }                                                                      \
    }                                                                        \
  }

  // 4-deep, two-level pipeline (payload 16-entry zero pad makes over-reads safe)
  unsigned p0 = payload[k0],     p1 = payload[k0 + 1];
  unsigned p2 = payload[k0 + 2], p3 = payload[k0 + 3];
  uint2 x0 = XLOAD(p0), x1 = XLOAD(p1), x2 = XLOAD(p2), x3 = XLOAD(p3);
  unsigned q0 = payload[k0 + 4], q1 = payload[k0 + 5];
  unsigned q2 = payload[k0 + 6], q3 = payload[k0 + 7];

  for (int k = k0; k < k1; k += 4) {
    const uint2 nx0 = XLOAD(q0), nx1 = XLOAD(q1);    // x for group g+1 (q* arrived)
    const uint2 nx2 = XLOAD(q2), nx3 = XLOAD(q3);
    const unsigned r0 = payload[k + 8],  r1 = payload[k + 9];   // payload for g+2
    const unsigned r2 = payload[k + 10], r3 = payload[k + 11];
    PROC(0, p0, x0) PROC(1, p1, x1) PROC(2, p2, x2) PROC(3, p3, x3)
    p0 = q0; p1 = q1; p2 = q2; p3 = q3;
    q0 = r0; q1 = r1; q2 = r2; q3 = r3;
    x0 = nx0; x1 = nx1; x2 = nx2; x3 = nx3;
  }

  const float iv = 1.0f / deg[n];
  const int nl = n - c0;
  unsigned short* vr = Vb + (size_t)nl * 4096 + (lane >> 4) * 64 +
                       ((((unsigned)(lane >> 1) & 7u) ^ (unsigned)(nl & 7)) << 3) +
                       (lane & 1) * 4;
#pragma unroll
  for (int b = 0; b < NB; ++b) {
    const unsigned short s0 = f2bf(acc2[b][0].x * iv);
    const unsigned short s1 = f2bf(acc2[b][0].y * iv);
    const unsigned short s2 = f2bf(acc2[b][1].x * iv);
    const unsigned short s3 = f2bf(acc2[b][1].y * iv);
    u32x2 pk;
    pk.x = (unsigned)s0 | ((unsigned)s1 << 16);
    pk.y = (unsigned)s2 | ((unsigned)s3 << 16);
    __builtin_nontemporal_store(pk, reinterpret_cast<u32x2*>(vr + (size_t)b * 256));
  }
}

// ---------- GEMM: out = [V/deg | x] @ bt^T, 64x128 tile, 2 waves, single-buf 24KB ----------
__global__ __launch_bounds__(128) void k_gemm6(
    const unsigned short* __restrict__ Vb, const unsigned short* __restrict__ xsw,
    const unsigned short* __restrict__ bt, float* __restrict__ out, const int c0) {
  __shared__ unsigned short As[64 * 64];             // 8 KB
  __shared__ unsigned short Bs[128 * 64];            // 16 KB
  const int t = threadIdx.x;
  const int rb = blockIdx.x, cb = blockIdx.y;
  const int lane = t & 63, w = t >> 6;               // 2 waves: cols w*64..+64
  const int lc = lane & 15, lg = lane >> 4;

  // staging roles: round covers 16 rows(A)/cols(B); row = r*16 + (t>>3), pos = t&7
  const int srow = t >> 3;                           // 0..15
  const int spos = t & 7;                            // chunk position (pre-swizzled src)
  const unsigned short* va[4];
  const unsigned short* xa[4];
  const unsigned short* bb[8];
#pragma unroll
  for (int a = 0; a < 4; ++a) {
    const int rl = a * 16 + srow;                    // 0..63 local row
    va[a] = Vb  + (size_t)(rb * 64 + rl) * 4096 + spos * 8;
    xa[a] = xsw + (size_t)(c0 + rb * 64 + rl) * 256 + spos * 8;
  }
#pragma unroll
  for (int b = 0; b < 8; ++b) {
    const int cl = b * 16 + srow;                    // 0..127 local col
    bb[b] = bt + (size_t)(cb * 128 + cl) * KK + spos * 8;
  }

#define GL(G, L) __builtin_amdgcn_global_load_lds(                            \
    (const __attribute__((address_space(1))) unsigned int*)(G),               \
    (__attribute__((address_space(3))) unsigned int*)(L), 16, 0, 0)

#define STAGE6(IT)                                                            \
  {                                                                           \
    const int it_ = (IT);                                                     \
    if (it_ < 64) {                                                           \
      _Pragma("unroll")                                                       \
      for (int a = 0; a < 4; ++a)                                             \
        GL(va[a] + it_ * 64, As + a * 1024 + (w << 9));                       \
    } else {                                                                  \
      _Pragma("unroll")                                                       \
      for (int a = 0; a < 4; ++a)                                             \
        GL(xa[a] + (it_ - 64) * 64, As + a * 1024 + (w << 9));                \
    }                                                                         \
    _Pragma("unroll")                                                         \
    for (int b = 0; b < 8; ++b)                                               \
      GL(bb[b] + it_ * 64, Bs + b * 1024 + (w << 9));                         \
  }

  f32x4 acc[4][4];
  const f32x4 zf = {0.f, 0.f, 0.f, 0.f};
#pragma unroll
  for (int m = 0; m < 4; ++m)
#pragma unroll
    for (int n = 0; n < 4; ++n) acc[m][n] = zf;

  for (int it = 0; it < GITER; ++it) {
    __syncthreads();                                 // previous iter's LDS reads done
    STAGE6(it);
    asm volatile("s_waitcnt vmcnt(0)" ::: "memory");
    __syncthreads();                                 // staged tile visible
#pragma unroll
    for (int kk = 0; kk < 2; ++kk) {
      bf16x8 af[4], bfm[4];
      const int ch = kk * 4 + lg;
#pragma unroll
      for (int m = 0; m < 4; ++m) {
        const int r2 = m * 16 + lc;                  // A rows 0..63
        af[m] = *reinterpret_cast<const bf16x8*>(&As[r2 * 64 + ((ch ^ (r2 & 7)) << 3)]);
      }
#pragma unroll
      for (int n = 0; n < 4; ++n) {
        const int c2 = w * 64 + n * 16 + lc;         // B cols per wave
        bfm[n] = *reinterpret_cast<const bf16x8*>(&Bs[c2 * 64 + ((ch ^ (c2 & 7)) << 3)]);
      }
#pragma unroll
      for (int m = 0; m < 4; ++m)
#pragma unroll
        for (int n = 0; n < 4; ++n)
          acc[m][n] = __builtin_amdgcn_mfma_f32_16x16x32_bf16(af[m], bfm[n], acc[m][n], 0, 0, 0);
    }
  }
#pragma unroll
  for (int m = 0; m < 4; ++m) {
#pragma unroll
    for (int j = 0; j < 4; ++j) {
      const int n = c0 + rb * 64 + m * 16 + lg * 4 + j;
      if (n < NN) {
        float* orow = out + (size_t)n * OUTD + cb * 128 + w * 64 + lc;
        __builtin_nontemporal_store(acc[m][0][j], orow + 0);
        __builtin_nontemporal_store(acc[m][1][j], orow + 16);
        __builtin_nontemporal_store(acc[m][2][j], orow + 32);
        __builtin_nontemporal_store(acc[m][3][j], orow + 48);
      }
    }
  }
}

extern "C" void kernel_launch(void* const* d_in, const int* in_sizes, int n_in,
                              void* d_out, int out_size, void* d_ws, size_t ws_size,
                              hipStream_t stream) {
  (void)in_sizes; (void)n_in; (void)out_size;
  const float* x     = (const float*)d_in[0];
  const float* att   = (const float*)d_in[1];
  const float* basis = (const float*)d_in[2];
  const float* root  = (const float*)d_in[3];
  const float* deg   = (const float*)d_in[4];
  const int*   esrc  = (const int*)d_in[5];
  const int*   edst  = (const int*)d_in[6];
  float* out = (float*)d_out;

  char* p = (char*)d_ws;
  unsigned short* xsw  = (unsigned short*)p; p += (size_t)NN * IND * 2;     // 25.6 MB
  unsigned short* bt   = (unsigned short*)p; p += (size_t)OUTD * KK * 2;    // 2.2 MB
  unsigned* payload    = (unsigned*)p;       p += (size_t)(NE + 16) * 4;    // 5.1 MB (+pad)
  int* rowptr          = (int*)p;            p += (size_t)(NN + 1) * 4;
  int* wof             = (int*)p;            p += (size_t)NN * 4;
  int* cnt             = (int*)p;            p += (size_t)NN * 4;
  int* bsum            = (int*)p;            p += 64 * 4;
  int* boff            = (int*)p;            p += 64 * 4;
  uintptr_t up = ((uintptr_t)p + 255) & ~(uintptr_t)255;
  unsigned short* Vb  = (unsigned short*)up;
  const size_t used = (size_t)((char*)Vb - (char*)d_ws);
  const size_t avail = ws_size - used;

  int chunk;
  if      (avail >= (size_t)(NN + 128) * 4096 * 2) chunk = NN;     // 410.7 MB: single pass
  else if (avail >= (size_t)25600 * 4096 * 2)      chunk = 25600;  // 209.7 MB
  else                                             chunk = 12800;

  hipMemsetAsync(cnt, 0, (size_t)NN * 4, stream);
  hipMemsetAsync(payload + NE, 0, 64, stream);       // zero the prefetch pad
  hipLaunchKernelGGL(k_xbf,     dim3(NN * IND / 2048), dim3(256),  0, stream, x, xsw);
  hipLaunchKernelGGL(k_hist,    dim3(NE / 256),        dim3(256),  0, stream, edst, cnt);
  hipLaunchKernelGGL(k_scan_a,  dim3(SCANB),           dim3(256),  0, stream, cnt, rowptr, bsum);
  hipLaunchKernelGGL(k_scan_b,  dim3(1),               dim3(64),   0, stream, bsum, boff, rowptr);
  hipLaunchKernelGGL(k_scan_c,  dim3(SCANB),           dim3(256),  0, stream, boff, rowptr, wof);
  hipLaunchKernelGGL(k_scatter, dim3(NE / 256),        dim3(256),  0, stream, esrc, edst, wof, payload);
  hipLaunchKernelGGL(k_bt,      dim3(OUTD),            dim3(256),  0, stream, basis, root, bt);

  for (int c0 = 0; c0 < NN; c0 += chunk) {
    const int rows = (NN - c0 < chunk) ? (NN - c0) : chunk;
    hipLaunchKernelGGL(k_vbuild, dim3((rows + 1) / 2), dim3(128), 0, stream,
                       xsw, att, deg, rowptr, payload, Vb, c0);
    hipLaunchKernelGGL(k_gemm6, dim3((rows + 63) / 64, 2), dim3(128), 0, stream,
                       Vb, xsw, bt, out, c0);
  }
}

// Round 17
// 589.419 us; speedup vs baseline: 1.0149x; 1.0110x over previous
//
#include <hip/hip_runtime.h>
#include <stdint.h>

#define NN 50000
#define RR 64
#define EE 20000
#define NB 16            // bases
#define IND 256
#define OUTD 256
#define KK 4352          // 16*256 (V) + 256 (x for root)
#define NE (RR * EE)     // 1,280,000 edges
#define GITER 68         // KK / 64
#define SCANB 49         // ceil(NN/1024)

typedef __attribute__((ext_vector_type(8))) short bf16x8;
typedef __attribute__((ext_vector_type(4))) float f32x4;
typedef __attribute__((ext_vector_type(2))) float f32x2;
typedef __attribute__((ext_vector_type(2))) unsigned int u32x2;

__device__ __forceinline__ unsigned short f2bf(float f) {
  union { float f; unsigned u; } v; v.f = f;
  unsigned r = v.u + 0x7FFFu + ((v.u >> 16) & 1u);   // RNE
  return (unsigned short)(r >> 16);
}
__device__ __forceinline__ float asf(unsigned u) {
  union { unsigned u; float f; } v; v.u = u; return v.f;
}

// ---------- x -> bf16, chunk-swizzled: chunk ch of row r stored at ch^(r&7) ----------
__global__ __launch_bounds__(256) void k_xbf(const float* __restrict__ x,
                                             unsigned short* __restrict__ xsw) {
  const int gt = blockIdx.x * 256 + threadIdx.x;     // one 8-elem chunk per thread
  const size_t g = (size_t)gt * 8;
  const int row = gt >> 5;                           // g / 256
  const int k = (gt & 31) * 8;                       // g % 256
  float4 v0 = *reinterpret_cast<const float4*>(x + g);
  float4 v1 = *reinterpret_cast<const float4*>(x + g + 4);
  union { bf16x8 v; unsigned short u[8]; } pk;
  pk.u[0]=f2bf(v0.x); pk.u[1]=f2bf(v0.y); pk.u[2]=f2bf(v0.z); pk.u[3]=f2bf(v0.w);
  pk.u[4]=f2bf(v1.x); pk.u[5]=f2bf(v1.y); pk.u[6]=f2bf(v1.z); pk.u[7]=f2bf(v1.w);
  const int tile = k >> 6, ch = (k >> 3) & 7;
  *reinterpret_cast<bf16x8*>(
      xsw + (size_t)row * 256 + tile * 64 + ((ch ^ (row & 7)) << 3)) = pk.v;
}

// ---------- counting sort of edges by dst ----------
__global__ __launch_bounds__(256) void k_hist(const int* __restrict__ edst,
                                              int* __restrict__ cnt) {
  const int g = blockIdx.x * 256 + threadIdx.x;
  atomicAdd(&cnt[edst[g]], 1);
}

__global__ __launch_bounds__(256) void k_scan_a(const int* __restrict__ cnt,
                                                int* __restrict__ rowptr,
                                                int* __restrict__ bsum) {
  __shared__ int ps[256];
  const int t = threadIdx.x, blk = blockIdx.x;
  const int base = blk * 1024 + t * 4;
  int v[4];
#pragma unroll
  for (int q = 0; q < 4; ++q) {
    const int idx = base + q;
    v[q] = (idx < NN) ? cnt[idx] : 0;
  }
  const int s = v[0] + v[1] + v[2] + v[3];
  ps[t] = s;
  __syncthreads();
  for (int off = 1; off < 256; off <<= 1) {
    const int u = (t >= off) ? ps[t - off] : 0;
    __syncthreads();
    ps[t] += u;
    __syncthreads();
  }
  int run = ps[t] - s;
#pragma unroll
  for (int q = 0; q < 4; ++q) {
    const int idx = base + q;
    if (idx < NN) rowptr[idx] = run;
    run += v[q];
  }
  if (t == 255) bsum[blk] = ps[255];
}

__global__ __launch_bounds__(64) void k_scan_b(const int* __restrict__ bsum,
                                               int* __restrict__ boff,
                                               int* __restrict__ rowptr) {
  const int t = threadIdx.x;
  const int own = (t < SCANB) ? bsum[t] : 0;
  int v = own;
  for (int off = 1; off < 64; off <<= 1) {
    const int u = __shfl_up(v, off);
    if (t >= off) v += u;
  }
  if (t < SCANB) boff[t] = v - own;
  if (t == SCANB - 1) rowptr[NN] = v;
}

__global__ __launch_bounds__(256) void k_scan_c(const int* __restrict__ boff,
                                                int* __restrict__ rowptr,
                                                int* __restrict__ wof) {
  const int t = threadIdx.x, blk = blockIdx.x;
  const int base = blk * 1024 + t * 4;
  const int bo = boff[blk];
#pragma unroll
  for (int q = 0; q < 4; ++q) {
    const int idx = base + q;
    if (idx < NN) {
      const int val = rowptr[idx] + bo;
      rowptr[idx] = val;
      wof[idx] = val;
    }
  }
}

__global__ __launch_bounds__(256) void k_scatter(const int* __restrict__ esrc,
                                                 const int* __restrict__ edst,
                                                 int* __restrict__ wof,
                                                 unsigned* __restrict__ payload) {
  const int g = blockIdx.x * 256 + threadIdx.x;
  const int d = edst[g];
  const int src = esrc[g];
  const int r = g / EE;
  const int pos = atomicAdd(&wof[d], 1);
  payload[pos] = ((unsigned)r << 18) | (unsigned)src;
}

// ---------- bt[o][k] bf16, chunk-swizzled by (o&7) ----------
__global__ __launch_bounds__(256) void k_bt(const float* __restrict__ basis,
                                            const float* __restrict__ root,
                                            unsigned short* __restrict__ bt) {
  const int o = blockIdx.x;
  for (int k = threadIdx.x; k < KK; k += 256) {
    float v;
    if (k < 4096) v = basis[(size_t)k * 256 + o];
    else          v = root[(size_t)(k - 4096) * 256 + o];
    const int tile = k >> 6, ch = (k >> 3) & 7;
    bt[(size_t)o * KK + tile * 64 + ((ch ^ (o & 7)) << 3) + (k & 7)] = f2bf(v);
  }
}

// ---------- V-build: one wave per dst; 4-deep pipelined gather; nt swizzle-baked V store ----------
__global__ __launch_bounds__(128) void k_vbuild(
    const unsigned short* __restrict__ xsw, const float* __restrict__ att,
    const float* __restrict__ deg, const int* __restrict__ rowptr,
    const unsigned* __restrict__ payload, unsigned short* __restrict__ Vb,
    const int c0) {
  __shared__ float attl[RR * NB];                    // 4 KB
  const int t = threadIdx.x;
  *reinterpret_cast<float4*>(&attl[t * 8]) =
      *reinterpret_cast<const float4*>(&att[t * 8]);
  *reinterpret_cast<float4*>(&attl[t * 8 + 4]) =
      *reinterpret_cast<const float4*>(&att[t * 8 + 4]);
  __syncthreads();
  const int lane = t & 63;
  const int n = c0 + blockIdx.x * 2 + (t >> 6);      // 2 waves/block: less imbalance
  if (n >= NN) return;
  const int k0 = rowptr[n], k1 = rowptr[n + 1];

  const int laneBase = (lane >> 4) * 64 + (lane & 1) * 4;
  const unsigned laneCh = (unsigned)((lane >> 1) & 7);

  f32x2 acc2[NB][2];
#pragma unroll
  for (int b = 0; b < NB; ++b) {
    acc2[b][0] = (f32x2){0.f, 0.f};
    acc2[b][1] = (f32x2){0.f, 0.f};
  }

#define XLOAD(PK)                                                            \
  (*reinterpret_cast<const uint2*>(                                          \
      xsw + (size_t)((PK) & 0x3FFFFu) * 256 + laneBase +                     \
      ((laneCh ^ ((PK) & 7u)) << 3)))

#define PROC(J, PK, XV)                                                      \
  {                                                                          \
    const bool ok_ = (k + (J)) < k1;                                         \
    const unsigned mx_ = ok_ ? (XV).x : 0u;                                  \
    const unsigned my_ = ok_ ? (XV).y : 0u;                                  \
    const int r_ = (int)((PK) >> 18);                                        \
    const f32x2 x01_ = {asf(mx_ << 16), asf(mx_ & 0xFFFF0000u)};             \
    const f32x2 x23_ = {asf(my_ << 16), asf(my_ & 0xFFFF0000u)};             \
    _Pragma("unroll")                                                        \
    for (int b4 = 0; b4 < 4; ++b4) {                                         \
      const float4 a4 = *reinterpret_cast<const float4*>(&attl[r_ * NB + b4 * 4]); \
      const float aa[4] = {a4.x, a4.y, a4.z, a4.w};                          \
      _Pragma("unroll")                                                      \
      for (int q = 0; q < 4; ++q) {                                          \
        const int b = b4 * 4 + q;                                            \
        acc2[b][0] += aa[q] * x01_;                                          \
        acc2[b][1] += aa[q] * x23_;                                          \
      }                                                                      \
    }                                                                        \
  }

  // 4-deep, two-level pipeline (payload 16-entry zero pad makes over-reads safe)
  unsigned p0 = payload[k0],     p1 = payload[k0 + 1];
  unsigned p2 = payload[k0 + 2], p3 = payload[k0 + 3];
  uint2 x0 = XLOAD(p0), x1 = XLOAD(p1), x2 = XLOAD(p2), x3 = XLOAD(p3);
  unsigned q0 = payload[k0 + 4], q1 = payload[k0 + 5];
  unsigned q2 = payload[k0 + 6], q3 = payload[k0 + 7];

  for (int k = k0; k < k1; k += 4) {
    const uint2 nx0 = XLOAD(q0), nx1 = XLOAD(q1);    // x for group g+1 (q* arrived)
    const uint2 nx2 = XLOAD(q2), nx3 = XLOAD(q3);
    const unsigned r0 = payload[k + 8],  r1 = payload[k + 9];   // payload for g+2
    const unsigned r2 = payload[k + 10], r3 = payload[k + 11];
    PROC(0, p0, x0) PROC(1, p1, x1) PROC(2, p2, x2) PROC(3, p3, x3)
    p0 = q0; p1 = q1; p2 = q2; p3 = q3;
    q0 = r0; q1 = r1; q2 = r2; q3 = r3;
    x0 = nx0; x1 = nx1; x2 = nx2; x3 = nx3;
  }

  const float iv = 1.0f / deg[n];
  const int nl = n - c0;
  unsigned short* vr = Vb + (size_t)nl * 4096 + (lane >> 4) * 64 +
                       ((((unsigned)(lane >> 1) & 7u) ^ (unsigned)(nl & 7)) << 3) +
                       (lane & 1) * 4;
#pragma unroll
  for (int b = 0; b < NB; ++b) {
    const unsigned short s0 = f2bf(acc2[b][0].x * iv);
    const unsigned short s1 = f2bf(acc2[b][0].y * iv);
    const unsigned short s2 = f2bf(acc2[b][1].x * iv);
    const unsigned short s3 = f2bf(acc2[b][1].y * iv);
    u32x2 pk;
    pk.x = (unsigned)s0 | ((unsigned)s1 << 16);
    pk.y = (unsigned)s2 | ((unsigned)s3 << 16);
    __builtin_nontemporal_store(pk, reinterpret_cast<u32x2*>(vr + (size_t)b * 256));
  }
}

// ---------- GEMM: out = [V/deg | x] @ bt^T, 64x128 tile, 2 waves, single-buf 24KB ----------
__global__ __launch_bounds__(128) void k_gemm6(
    const unsigned short* __restrict__ Vb, const unsigned short* __restrict__ xsw,
    const unsigned short* __restrict__ bt, float* __restrict__ out, const int c0) {
  __shared__ unsigned short As[64 * 64];             // 8 KB
  __shared__ unsigned short Bs[128 * 64];            // 16 KB
  const int t = threadIdx.x;
  const int rb = blockIdx.x, cb = blockIdx.y;
  const int lane = t & 63, w = t >> 6;               // 2 waves: cols w*64..+64
  const int lc = lane & 15, lg = lane >> 4;

  // staging roles: round covers 16 rows(A)/cols(B); row = r*16 + (t>>3), pos = t&7
  const int srow = t >> 3;                           // 0..15
  const int spos = t & 7;                            // chunk position (pre-swizzled src)
  const unsigned short* va[4];
  const unsigned short* xa[4];
  const unsigned short* bb[8];
#pragma unroll
  for (int a = 0; a < 4; ++a) {
    const int rl = a * 16 + srow;                    // 0..63 local row
    va[a] = Vb  + (size_t)(rb * 64 + rl) * 4096 + spos * 8;
    xa[a] = xsw + (size_t)(c0 + rb * 64 + rl) * 256 + spos * 8;
  }
#pragma unroll
  for (int b = 0; b < 8; ++b) {
    const int cl = b * 16 + srow;                    // 0..127 local col
    bb[b] = bt + (size_t)(cb * 128 + cl) * KK + spos * 8;
  }

#define GL(G, L) __builtin_amdgcn_global_load_lds(                            \
    (const __attribute__((address_space(1))) unsigned int*)(G),               \
    (__attribute__((address_space(3))) unsigned int*)(L), 16, 0, 0)

#define STAGE6(IT)                                                            \
  {                                                                           \
    const int it_ = (IT);                                                     \
    if (it_ < 64) {                                                           \
      _Pragma("unroll")                                                       \
      for (int a = 0; a < 4; ++a)                                             \
        GL(va[a] + it_ * 64, As + a * 1024 + (w << 9));                       \
    } else {                                                                  \
      _Pragma("unroll")                                                       \
      for (int a = 0; a < 4; ++a)                                             \
        GL(xa[a] + (it_ - 64) * 64, As + a * 1024 + (w << 9));                \
    }                                                                         \
    _Pragma("unroll")                                                         \
    for (int b = 0; b < 8; ++b)                                               \
      GL(bb[b] + it_ * 64, Bs + b * 1024 + (w << 9));                         \
  }

  f32x4 acc[4][4];
  const f32x4 zf = {0.f, 0.f, 0.f, 0.f};
#pragma unroll
  for (int m = 0; m < 4; ++m)
#pragma unroll
    for (int n = 0; n < 4; ++n) acc[m][n] = zf;

  for (int it = 0; it < GITER; ++it) {
    __syncthreads();                                 // previous iter's LDS reads done
    STAGE6(it);
    asm volatile("s_waitcnt vmcnt(0)" ::: "memory");
    __syncthreads();                                 // staged tile visible
#pragma unroll
    for (int kk = 0; kk < 2; ++kk) {
      bf16x8 af[4], bfm[4];
      const int ch = kk * 4 + lg;
#pragma unroll
      for (int m = 0; m < 4; ++m) {
        const int r2 = m * 16 + lc;                  // A rows 0..63
        af[m] = *reinterpret_cast<const bf16x8*>(&As[r2 * 64 + ((ch ^ (r2 & 7)) << 3)]);
      }
#pragma unroll
      for (int n = 0; n < 4; ++n) {
        const int c2 = w * 64 + n * 16 + lc;         // B cols per wave
        bfm[n] = *reinterpret_cast<const bf16x8*>(&Bs[c2 * 64 + ((ch ^ (c2 & 7)) << 3)]);
      }
#pragma unroll
      for (int m = 0; m < 4; ++m)
#pragma unroll
        for (int n = 0; n < 4; ++n)
          acc[m][n] = __builtin_amdgcn_mfma_f32_16x16x32_bf16(af[m], bfm[n], acc[m][n], 0, 0, 0);
    }
  }
#pragma unroll
  for (int m = 0; m < 4; ++m) {
#pragma unroll
    for (int j = 0; j < 4; ++j) {
      const int n = c0 + rb * 64 + m * 16 + lg * 4 + j;
      if (n < NN) {
        float* orow = out + (size_t)n * OUTD + cb * 128 + w * 64 + lc;
        __builtin_nontemporal_store(acc[m][0][j], orow + 0);
        __builtin_nontemporal_store(acc[m][1][j], orow + 16);
        __builtin_nontemporal_store(acc[m][2][j], orow + 32);
        __builtin_nontemporal_store(acc[m][3][j], orow + 48);
      }
    }
  }
}

extern "C" void kernel_launch(void* const* d_in, const int* in_sizes, int n_in,
                              void* d_out, int out_size, void* d_ws, size_t ws_size,
                              hipStream_t stream) {
  (void)in_sizes; (void)n_in; (void)out_size;
  const float* x     = (const float*)d_in[0];
  const float* att   = (const float*)d_in[1];
  const float* basis = (const float*)d_in[2];
  const float* root  = (const float*)d_in[3];
  const float* deg   = (const float*)d_in[4];
  const int*   esrc  = (const int*)d_in[5];
  const int*   edst  = (const int*)d_in[6];
  float* out = (float*)d_out;

  char* p = (char*)d_ws;
  unsigned short* xsw  = (unsigned short*)p; p += (size_t)NN * IND * 2;     // 25.6 MB
  unsigned short* bt   = (unsigned short*)p; p += (size_t)OUTD * KK * 2;    // 2.2 MB
  unsigned* payload    = (unsigned*)p;       p += (size_t)(NE + 16) * 4;    // 5.1 MB (+pad)
  int* rowptr          = (int*)p;            p += (size_t)(NN + 1) * 4;
  int* wof             = (int*)p;            p += (size_t)NN * 4;
  int* cnt             = (int*)p;            p += (size_t)NN * 4;
  int* bsum            = (int*)p;            p += 64 * 4;
  int* boff            = (int*)p;            p += 64 * 4;
  uintptr_t up = ((uintptr_t)p + 255) & ~(uintptr_t)255;
  unsigned short* Vb  = (unsigned short*)up;
  const size_t used = (size_t)((char*)Vb - (char*)d_ws);
  const size_t avail = ws_size - used;

  int chunk;
  if      (avail >= (size_t)(NN + 128) * 4096 * 2) chunk = NN;     // 410.7 MB: single pass
  else if (avail >= (size_t)25600 * 4096 * 2)      chunk = 25600;  // 209.7 MB
  else                                             chunk = 12800;

  hipMemsetAsync(cnt, 0, (size_t)NN * 4, stream);
  hipMemsetAsync(payload + NE, 0, 64, stream);       // zero the prefetch pad
  hipLaunchKernelGGL(k_xbf,     dim3(NN * IND / 2048), dim3(256),  0, stream, x, xsw);
  hipLaunchKernelGGL(k_hist,    dim3(NE / 256),        dim3(256),  0, stream, edst, cnt);
  hipLaunchKernelGGL(k_scan_a,  dim3(SCANB),           dim3(256),  0, stream, cnt, rowptr, bsum);
  hipLaunchKernelGGL(k_scan_b,  dim3(1),               dim3(64),   0, stream, bsum, boff, rowptr);
  hipLaunchKernelGGL(k_scan_c,  dim3(SCANB),           dim3(256),  0, stream, boff, rowptr, wof);
  hipLaunchKernelGGL(k_scatter, dim3(NE / 256),        dim3(256),  0, stream, esrc, edst, wof, payload);
  hipLaunchKernelGGL(k_bt,      dim3(OUTD),            dim3(256),  0, stream, basis, root, bt);

  for (int c0 = 0; c0 < NN; c0 += chunk) {
    const int rows = (NN - c0 < chunk) ? (NN - c0) : chunk;
    hipLaunchKernelGGL(k_vbuild, dim3((rows + 1) / 2), dim3(128), 0, stream,
                       xsw, att, deg, rowptr, payload, Vb, c0);
    hipLaunchKernelGGL(k_gemm6, dim3((rows + 63) / 64, 2), dim3(128), 0, stream,
                       Vb, xsw, bt, out, c0);
  }
}

// Round 18
// 537.482 us; speedup vs baseline: 1.1130x; 1.0966x over previous
//
#include <hip/hip_runtime.h>
#include <stdint.h>

#define NN 50000
#define RR 64
#define EE 20000
#define NB 16            // bases
#define IND 256
#define OUTD 256
#define KK 4352          // 16*256 (V) + 256 (x for root)
#define NE (RR * EE)     // 1,280,000 edges
#define GITER 68         // KK / 64
#define SCANB 49         // ceil(NN/1024)
#define NSEG 8           // XCD count; dst range per segment
#define SEGW 6250        // NN / NSEG

typedef __attribute__((ext_vector_type(8))) short bf16x8;
typedef __attribute__((ext_vector_type(4))) float f32x4;
typedef __attribute__((ext_vector_type(2))) float f32x2;
typedef __attribute__((ext_vector_type(2))) unsigned int u32x2;

__device__ __forceinline__ unsigned short f2bf(float f) {
  union { float f; unsigned u; } v; v.f = f;
  unsigned r = v.u + 0x7FFFu + ((v.u >> 16) & 1u);   // RNE
  return (unsigned short)(r >> 16);
}
__device__ __forceinline__ float asf(unsigned u) {
  union { unsigned u; float f; } v; v.u = u; return v.f;
}

// ---------- x -> bf16, chunk-swizzled: chunk ch of row r stored at ch^(r&7) ----------
__global__ __launch_bounds__(256) void k_xbf(const float* __restrict__ x,
                                             unsigned short* __restrict__ xsw) {
  const int gt = blockIdx.x * 256 + threadIdx.x;     // one 8-elem chunk per thread
  const size_t g = (size_t)gt * 8;
  const int row = gt >> 5;                           // g / 256
  const int k = (gt & 31) * 8;                       // g % 256
  float4 v0 = *reinterpret_cast<const float4*>(x + g);
  float4 v1 = *reinterpret_cast<const float4*>(x + g + 4);
  union { bf16x8 v; unsigned short u[8]; } pk;
  pk.u[0]=f2bf(v0.x); pk.u[1]=f2bf(v0.y); pk.u[2]=f2bf(v0.z); pk.u[3]=f2bf(v0.w);
  pk.u[4]=f2bf(v1.x); pk.u[5]=f2bf(v1.y); pk.u[6]=f2bf(v1.z); pk.u[7]=f2bf(v1.w);
  const int tile = k >> 6, ch = (k >> 3) & 7;
  *reinterpret_cast<bf16x8*>(
      xsw + (size_t)row * 256 + tile * 64 + ((ch ^ (row & 7)) << 3)) = pk.v;
}

// ---------- counting sort of edges by dst ----------
__global__ __launch_bounds__(256) void k_hist(const int* __restrict__ edst,
                                              int* __restrict__ cnt) {
  const int g = blockIdx.x * 256 + threadIdx.x;
  atomicAdd(&cnt[edst[g]], 1);
}

__global__ __launch_bounds__(256) void k_scan_a(const int* __restrict__ cnt,
                                                int* __restrict__ rowptr,
                                                int* __restrict__ bsum) {
  __shared__ int ps[256];
  const int t = threadIdx.x, blk = blockIdx.x;
  const int base = blk * 1024 + t * 4;
  int v[4];
#pragma unroll
  for (int q = 0; q < 4; ++q) {
    const int idx = base + q;
    v[q] = (idx < NN) ? cnt[idx] : 0;
  }
  const int s = v[0] + v[1] + v[2] + v[3];
  ps[t] = s;
  __syncthreads();
  for (int off = 1; off < 256; off <<= 1) {
    const int u = (t >= off) ? ps[t - off] : 0;
    __syncthreads();
    ps[t] += u;
    __syncthreads();
  }
  int run = ps[t] - s;
#pragma unroll
  for (int q = 0; q < 4; ++q) {
    const int idx = base + q;
    if (idx < NN) rowptr[idx] = run;
    run += v[q];
  }
  if (t == 255) bsum[blk] = ps[255];
}

__global__ __launch_bounds__(64) void k_scan_b(const int* __restrict__ bsum,
                                               int* __restrict__ boff,
                                               int* __restrict__ rowptr) {
  const int t = threadIdx.x;
  const int own = (t < SCANB) ? bsum[t] : 0;
  int v = own;
  for (int off = 1; off < 64; off <<= 1) {
    const int u = __shfl_up(v, off);
    if (t >= off) v += u;
  }
  if (t < SCANB) boff[t] = v - own;
  if (t == SCANB - 1) rowptr[NN] = v;
}

__global__ __launch_bounds__(256) void k_scan_c(const int* __restrict__ boff,
                                                int* __restrict__ rowptr,
                                                int* __restrict__ wof) {
  const int t = threadIdx.x, blk = blockIdx.x;
  const int base = blk * 1024 + t * 4;
  const int bo = boff[blk];
#pragma unroll
  for (int q = 0; q < 4; ++q) {
    const int idx = base + q;
    if (idx < NN) {
      const int val = rowptr[idx] + bo;
      rowptr[idx] = val;
      wof[idx] = val;
    }
  }
}

// ---------- XCD-partitioned scatter: group g = bid&7 writes only dst in its range ----------
// Payload writes for one group land in a contiguous ~640 KB window, private to one
// XCD's L2 (blocks with equal bid&7 dispatch to the same XCD) -> lines absorb all
// ~16 edge-writes before eviction instead of one HBM line round-trip per edge.
__global__ __launch_bounds__(256) void k_scatter(const int* __restrict__ esrc,
                                                 const int* __restrict__ edst,
                                                 int* __restrict__ wof,
                                                 unsigned* __restrict__ payload) {
  const int grp = blockIdx.x & 7;
  const int seg = blockIdx.x >> 3;
  const int g = seg * 256 + threadIdx.x;
  const int d = edst[g];
  const int lo = grp * SEGW;
  if (d < lo || d >= lo + SEGW) return;
  const int src = esrc[g];
  const int r = g / EE;
  const int pos = atomicAdd(&wof[d], 1);
  payload[pos] = ((unsigned)r << 18) | (unsigned)src;
}

// ---------- bt[o][k] bf16, chunk-swizzled by (o&7) ----------
__global__ __launch_bounds__(256) void k_bt(const float* __restrict__ basis,
                                            const float* __restrict__ root,
                                            unsigned short* __restrict__ bt) {
  const int o = blockIdx.x;
  for (int k = threadIdx.x; k < KK; k += 256) {
    float v;
    if (k < 4096) v = basis[(size_t)k * 256 + o];
    else          v = root[(size_t)(k - 4096) * 256 + o];
    const int tile = k >> 6, ch = (k >> 3) & 7;
    bt[(size_t)o * KK + tile * 64 + ((ch ^ (o & 7)) << 3) + (k & 7)] = f2bf(v);
  }
}

// ---------- V-build: one wave per dst; 4-deep pipelined gather; nt swizzle-baked V store ----------
__global__ __launch_bounds__(128) void k_vbuild(
    const unsigned short* __restrict__ xsw, const float* __restrict__ att,
    const float* __restrict__ deg, const int* __restrict__ rowptr,
    const unsigned* __restrict__ payload, unsigned short* __restrict__ Vb,
    const int c0) {
  __shared__ float attl[RR * NB];                    // 4 KB
  const int t = threadIdx.x;
  *reinterpret_cast<float4*>(&attl[t * 8]) =
      *reinterpret_cast<const float4*>(&att[t * 8]);
  *reinterpret_cast<float4*>(&attl[t * 8 + 4]) =
      *reinterpret_cast<const float4*>(&att[t * 8 + 4]);
  __syncthreads();
  const int lane = t & 63;
  const int n = c0 + blockIdx.x * 2 + (t >> 6);      // 2 waves/block: less imbalance
  if (n >= NN) return;
  const int k0 = rowptr[n], k1 = rowptr[n + 1];

  const int laneBase = (lane >> 4) * 64 + (lane & 1) * 4;
  const unsigned laneCh = (unsigned)((lane >> 1) & 7);

  f32x2 acc2[NB][2];
#pragma unroll
  for (int b = 0; b < NB; ++b) {
    acc2[b][0] = (f32x2){0.f, 0.f};
    acc2[b][1] = (f32x2){0.f, 0.f};
  }

#define XLOAD(PK)                                                            \
  (*reinterpret_cast<const uint2*>(                                          \
      xsw + (size_t)((PK) & 0x3FFFFu) * 256 + laneBase +                     \
      ((laneCh ^ ((PK) & 7u)) << 3)))

#define PROC(J, PK, XV)                                                      \
  {                                                                          \
    const bool ok_ = (k + (J)) < k1;                                         \
    const unsigned mx_ = ok_ ? (XV).x : 0u;                                  \
    const unsigned my_ = ok_ ? (XV).y : 0u;                                  \
    const int r_ = (int)((PK) >> 18);                                        \
    const f32x2 x01_ = {asf(mx_ << 16), asf(mx_ & 0xFFFF0000u)};             \
    const f32x2 x23_ = {asf(my_ << 16), asf(my_ & 0xFFFF0000u)};             \
    _Pragma("unroll")                                                        \
    for (int b4 = 0; b4 < 4; ++b4) {                                         \
      const float4 a4 = *reinterpret_cast<const float4*>(&attl[r_ * NB + b4 * 4]); \
      const float aa[4] = {a4.x, a4.y, a4.z, a4.w};                          \
      _Pragma("unroll")                                                      \
      for (int q = 0; q < 4; ++q) {                                          \
        const int b = b4 * 4 + q;                                            \
        acc2[b][0] += aa[q] * x01_;                                          \
        acc2[b][1] += aa[q] * x23_;                                          \
      }                                                                      \
    }                                                                        \
  }

  // 4-deep, two-level pipeline (payload 16-entry zero pad makes over-reads safe)
  unsigned p0 = payload[k0],     p1 = payload[k0 + 1];
  unsigned p2 = payload[k0 + 2], p3 = payload[k0 + 3];
  uint2 x0 = XLOAD(p0), x1 = XLOAD(p1), x2 = XLOAD(p2), x3 = XLOAD(p3);
  unsigned q0 = payload[k0 + 4], q1 = payload[k0 + 5];
  unsigned q2 = payload[k0 + 6], q3 = payload[k0 + 7];

  for (int k = k0; k < k1; k += 4) {
    const uint2 nx0 = XLOAD(q0), nx1 = XLOAD(q1);    // x for group g+1 (q* arrived)
    const uint2 nx2 = XLOAD(q2), nx3 = XLOAD(q3);
    const unsigned r0 = payload[k + 8],  r1 = payload[k + 9];   // payload for g+2
    const unsigned r2 = payload[k + 10], r3 = payload[k + 11];
    PROC(0, p0, x0) PROC(1, p1, x1) PROC(2, p2, x2) PROC(3, p3, x3)
    p0 = q0; p1 = q1; p2 = q2; p3 = q3;
    q0 = r0; q1 = r1; q2 = r2; q3 = r3;
    x0 = nx0; x1 = nx1; x2 = nx2; x3 = nx3;
  }

  const float iv = 1.0f / deg[n];
  const int nl = n - c0;
  unsigned short* vr = Vb + (size_t)nl * 4096 + (lane >> 4) * 64 +
                       ((((unsigned)(lane >> 1) & 7u) ^ (unsigned)(nl & 7)) << 3) +
                       (lane & 1) * 4;
#pragma unroll
  for (int b = 0; b < NB; ++b) {
    const unsigned short s0 = f2bf(acc2[b][0].x * iv);
    const unsigned short s1 = f2bf(acc2[b][0].y * iv);
    const unsigned short s2 = f2bf(acc2[b][1].x * iv);
    const unsigned short s3 = f2bf(acc2[b][1].y * iv);
    u32x2 pk;
    pk.x = (unsigned)s0 | ((unsigned)s1 << 16);
    pk.y = (unsigned)s2 | ((unsigned)s3 << 16);
    __builtin_nontemporal_store(pk, reinterpret_cast<u32x2*>(vr + (size_t)b * 256));
  }
}

// ---------- GEMM: out = [V/deg | x] @ bt^T, 128x128 tile, dbuf + global_load_lds ----------
__global__ __launch_bounds__(256) void k_gemm4(
    const unsigned short* __restrict__ Vb, const unsigned short* __restrict__ xsw,
    const unsigned short* __restrict__ bt, float* __restrict__ out, const int c0) {
  __shared__ unsigned short As[2][128 * 64];         // 16 KB each
  __shared__ unsigned short Bs[2][128 * 64];         // 16 KB each
  const int t = threadIdx.x;
  const int rb = blockIdx.x, cb = blockIdx.y;
  const int lane = t & 63, w = t >> 6;
  const int wr = w >> 1, wc = w & 1;                 // 2x2 waves of 64x64
  const int lc = lane & 15, lg = lane >> 4;

  const int lrow8 = lane >> 3;                       // 0..7
  const int lchk  = lane & 7;                        // 0..7
  const int arow0 = rb * 128 + w * 32 + lrow8;       // chunk-local A row (+ i*8)
  const int bcol0 = cb * 128 + w * 32 + lrow8;       // global B col (+ i*8)
  const unsigned short* vrow = Vb  + (size_t)arow0 * 4096 + lchk * 8;
  const unsigned short* xrow = xsw + (size_t)(c0 + arow0) * 256 + lchk * 8;
  const unsigned short* brow = bt  + (size_t)bcol0 * KK + lchk * 8;

#define GL(G, L) __builtin_amdgcn_global_load_lds(                            \
    (const __attribute__((address_space(1))) unsigned int*)(G),               \
    (__attribute__((address_space(3))) unsigned int*)(L), 16, 0, 0)

#define STAGE4(IT, BUF)                                                       \
  {                                                                           \
    const int it_ = (IT);                                                     \
    unsigned short* abase = &As[BUF][w * 2048];                               \
    unsigned short* bbase = &Bs[BUF][w * 2048];                               \
    if (it_ < 64) {                                                           \
      const unsigned short* ga = vrow + it_ * 64;                             \
      _Pragma("unroll")                                                       \
      for (int i = 0; i < 4; ++i) GL(ga + (size_t)i * 8 * 4096, abase + i * 512); \
    } else {                                                                  \
      const unsigned short* ga = xrow + (it_ - 64) * 64;                      \
      _Pragma("unroll")                                                       \
      for (int i = 0; i < 4; ++i) GL(ga + (size_t)i * 8 * 256, abase + i * 512); \
    }                                                                         \
    const unsigned short* gb = brow + it_ * 64;                               \
    _Pragma("unroll")                                                         \
    for (int i = 0; i < 4; ++i) GL(gb + (size_t)i * 8 * KK, bbase + i * 512); \
  }

  f32x4 acc[4][4];
  const f32x4 zf = {0.f, 0.f, 0.f, 0.f};
#pragma unroll
  for (int m = 0; m < 4; ++m)
#pragma unroll
    for (int n = 0; n < 4; ++n) acc[m][n] = zf;

  STAGE4(0, 0);
  asm volatile("s_waitcnt vmcnt(0)" ::: "memory");
  __syncthreads();
  int cur = 0;
  for (int it = 0; it < GITER; ++it) {
    if (it + 1 < GITER) STAGE4(it + 1, cur ^ 1);     // async loads overlap MFMA
#pragma unroll
    for (int kk = 0; kk < 2; ++kk) {
      bf16x8 af[4], bfm[4];
      const int ch = kk * 4 + lg;
#pragma unroll
      for (int m = 0; m < 4; ++m) {
        const int r2 = wr * 64 + m * 16 + lc;
        af[m] = *reinterpret_cast<const bf16x8*>(&As[cur][r2 * 64 + ((ch ^ (r2 & 7)) << 3)]);
      }
#pragma unroll
      for (int n = 0; n < 4; ++n) {
        const int c2 = wc * 64 + n * 16 + lc;
        bfm[n] = *reinterpret_cast<const bf16x8*>(&Bs[cur][c2 * 64 + ((ch ^ (c2 & 7)) << 3)]);
      }
#pragma unroll
      for (int m = 0; m < 4; ++m)
#pragma unroll
        for (int n = 0; n < 4; ++n)
          acc[m][n] = __builtin_amdgcn_mfma_f32_16x16x32_bf16(af[m], bfm[n], acc[m][n], 0, 0, 0);
    }
    asm volatile("s_waitcnt vmcnt(0)" ::: "memory"); // drain staged loads before barrier
    __syncthreads();
    cur ^= 1;
  }
#pragma unroll
  for (int m = 0; m < 4; ++m) {
#pragma unroll
    for (int j = 0; j < 4; ++j) {
      const int n = c0 + rb * 128 + wr * 64 + m * 16 + lg * 4 + j;
      if (n < NN) {
        float* orow = out + (size_t)n * OUTD + cb * 128 + wc * 64 + lc;
        __builtin_nontemporal_store(acc[m][0][j], orow + 0);
        __builtin_nontemporal_store(acc[m][1][j], orow + 16);
        __builtin_nontemporal_store(acc[m][2][j], orow + 32);
        __builtin_nontemporal_store(acc[m][3][j], orow + 48);
      }
    }
  }
}

extern "C" void kernel_launch(void* const* d_in, const int* in_sizes, int n_in,
                              void* d_out, int out_size, void* d_ws, size_t ws_size,
                              hipStream_t stream) {
  (void)in_sizes; (void)n_in; (void)out_size;
  const float* x     = (const float*)d_in[0];
  const float* att   = (const float*)d_in[1];
  const float* basis = (const float*)d_in[2];
  const float* root  = (const float*)d_in[3];
  const float* deg   = (const float*)d_in[4];
  const int*   esrc  = (const int*)d_in[5];
  const int*   edst  = (const int*)d_in[6];
  float* out = (float*)d_out;

  char* p = (char*)d_ws;
  unsigned short* xsw  = (unsigned short*)p; p += (size_t)NN * IND * 2;     // 25.6 MB
  unsigned short* bt   = (unsigned short*)p; p += (size_t)OUTD * KK * 2;    // 2.2 MB
  unsigned* payload    = (unsigned*)p;       p += (size_t)(NE + 16) * 4;    // 5.1 MB (+pad)
  int* rowptr          = (int*)p;            p += (size_t)(NN + 1) * 4;
  int* wof             = (int*)p;            p += (size_t)NN * 4;
  int* cnt             = (int*)p;            p += (size_t)NN * 4;
  int* bsum            = (int*)p;            p += 64 * 4;
  int* boff            = (int*)p;            p += 64 * 4;
  uintptr_t up = ((uintptr_t)p + 255) & ~(uintptr_t)255;
  unsigned short* Vb  = (unsigned short*)up;
  const size_t used = (size_t)((char*)Vb - (char*)d_ws);
  const size_t avail = ws_size - used;

  int chunk;
  if      (avail >= (size_t)(NN + 128) * 4096 * 2) chunk = NN;     // 410.7 MB: single pass
  else if (avail >= (size_t)25600 * 4096 * 2)      chunk = 25600;  // 209.7 MB
  else                                             chunk = 12800;

  hipMemsetAsync(cnt, 0, (size_t)NN * 4, stream);
  hipMemsetAsync(payload + NE, 0, 64, stream);       // zero the prefetch pad
  hipLaunchKernelGGL(k_xbf,     dim3(NN * IND / 2048),  dim3(256),  0, stream, x, xsw);
  hipLaunchKernelGGL(k_hist,    dim3(NE / 256),         dim3(256),  0, stream, edst, cnt);
  hipLaunchKernelGGL(k_scan_a,  dim3(SCANB),            dim3(256),  0, stream, cnt, rowptr, bsum);
  hipLaunchKernelGGL(k_scan_b,  dim3(1),                dim3(64),   0, stream, bsum, boff, rowptr);
  hipLaunchKernelGGL(k_scan_c,  dim3(SCANB),            dim3(256),  0, stream, boff, rowptr, wof);
  hipLaunchKernelGGL(k_scatter, dim3(NE / 256 * NSEG),  dim3(256),  0, stream, esrc, edst, wof, payload);
  hipLaunchKernelGGL(k_bt,      dim3(OUTD),             dim3(256),  0, stream, basis, root, bt);

  for (int c0 = 0; c0 < NN; c0 += chunk) {
    const int rows = (NN - c0 < chunk) ? (NN - c0) : chunk;
    hipLaunchKernelGGL(k_vbuild, dim3((rows + 1) / 2), dim3(128), 0, stream,
                       xsw, att, deg, rowptr, payload, Vb, c0);
    hipLaunchKernelGGL(k_gemm4, dim3((rows + 127) / 128, 2), dim3(256), 0, stream,
                       Vb, xsw, bt, out, c0);
  }
}